// Round 8
// baseline (148.493 us; speedup 1.0000x reference)
//
#include <hip/hip_runtime.h>

typedef unsigned long long u64;
typedef unsigned int u32;

#define FEAT_W 100
#define NANCH 9
#define NTOT 57600
#define NPAD 65536
#define PRE_NMS 6000
#define POST_NMS 300
#define NBLK 94        // 64-box blocks (mask words per full row)
#define NCHUNK 24      // 4 words (256 boxes) per k_scan iteration
#define CH_STRIDE 6400
#define CHUNK 1024
#define CAP 6144

__constant__ double c_base[9][4] = {
    {-84.0, -40.0, 99.0, 55.0},    {-176.0, -88.0, 191.0, 103.0},
    {-360.0, -184.0, 375.0, 199.0},{-56.0, -56.0, 71.0, 71.0},
    {-120.0, -120.0, 135.0, 135.0},{-248.0, -248.0, 263.0, 263.0},
    {-36.0, -80.0, 51.0, 95.0},    {-80.0, -168.0, 95.0, 183.0},
    {-168.0, -344.0, 183.0, 359.0}};

struct BoxD { double x1, y1, x2, y2; };

// Packed upper-triangular mask: row i stores words [i>>6, 94).
__device__ __forceinline__ int packed_off(int i) {
  int q = i >> 6, r = i & 63;
  return 94 * i - 32 * q * (q - 1) - r * q;
}

__device__ __forceinline__ BoxD decode_box(int i, const float* __restrict__ bbox,
                                           double imw1, double imh1) {
  int pos = i / NANCH;
  int a = i - pos * NANCH;
  int h = pos / FEAT_W;
  int w = pos - h * FEAT_W;
  double ax1 = c_base[a][0] + 16.0 * (double)w;
  double ay1 = c_base[a][1] + 16.0 * (double)h;
  double ax2 = c_base[a][2] + 16.0 * (double)w;
  double ay2 = c_base[a][3] + 16.0 * (double)h;
  double wd = ax2 - ax1 + 1.0;
  double hg = ay2 - ay1 + 1.0;
  double cx = ax1 + 0.5 * wd;
  double cy = ay1 + 0.5 * hg;
  const float* bp = bbox + (size_t)(4 * a) * CH_STRIDE + pos;
  double dx = (double)bp[0];
  double dy = (double)bp[CH_STRIDE];
  double dw = (double)bp[2 * CH_STRIDE];
  double dh = (double)bp[3 * CH_STRIDE];
  double pcx = dx * wd + cx;
  double pcy = dy * hg + cy;
  double pw = exp(dw) * wd;
  double ph = exp(dh) * hg;
  BoxD b;
  b.x1 = fmin(fmax(pcx - 0.5 * pw, 0.0), imw1);
  b.y1 = fmin(fmax(pcy - 0.5 * ph, 0.0), imh1);
  b.x2 = fmin(fmax(pcx + 0.5 * pw, 0.0), imw1);
  b.y2 = fmin(fmax(pcy + 0.5 * ph, 0.0), imh1);
  return b;
}

__device__ __forceinline__ u64 score_key(int i, const float* __restrict__ cls,
                                         const float* __restrict__ bbox,
                                         double imw1, double imh1) {
  BoxD b = decode_box(i, bbox, imw1, imh1);
  bool valid = (b.x2 - b.x1 + 1.0 >= 16.0) && (b.y2 - b.y1 + 1.0 >= 16.0);
  int pos = i / NANCH;
  int a = i - pos * NANCH;
  double c0 = (double)cls[(size_t)(2 * a) * CH_STRIDE + pos];
  double c1 = (double)cls[(size_t)(2 * a + 1) * CH_STRIDE + pos];
  double m = fmax(c0, c1);
  double e0 = exp(c0 - m), e1 = exp(c1 - m);
  double s = e1 / (e0 + e1);
  double masked = valid ? s : (double)(-1e30f);
  u64 u = (u64)__double_as_longlong(masked);
  return (u >> 63) ? ~u : (u | 0x8000000000000000ULL);
}

__device__ __forceinline__ bool before(u64 ka, u32 va, u64 kb, u32 vb) {
  return (ka > kb) || (ka == kb && va < vb);
}
__device__ __forceinline__ bool comes_after(u64 ka, u32 va, u64 kb, u32 vb) {
  return (ka < kb) || (ka == kb && va > vb);
}

// 64 blocks: compute 1024 keys, bitonic-sort in LDS, write chunk.
// Barriers only at cross-wave stages (j >= 128) and transitions out of one.
__global__ __launch_bounds__(512) void k_score_sort(
    const float* __restrict__ cls, const float* __restrict__ bbox,
    const int* __restrict__ imh, const int* __restrict__ imw,
    u64* __restrict__ keys, u32* __restrict__ vals) {
  __shared__ u64 sk[CHUNK];
  __shared__ u32 sv[CHUNK];
  int base = blockIdx.x * CHUNK;
  double imh1 = (double)(imh[0] - 1);
  double imw1 = (double)(imw[0] - 1);
  for (int t = threadIdx.x; t < CHUNK; t += 512) {
    int i = base + t;
    if (i < NTOT) { sk[t] = score_key(i, cls, bbox, imw1, imh1); sv[t] = (u32)i; }
    else { sk[t] = 0ULL; sv[t] = (u32)i; }
  }
  __syncthreads();
  bool prev_cross = false;
  for (int k = 2; k <= CHUNK; k <<= 1) {
    for (int j = k >> 1; j > 0; j >>= 1) {
      bool cross = (j >= 128);
      if (cross || prev_cross) __syncthreads();
      int t = threadIdx.x;
      int i = ((t & ~(j - 1)) << 1) | (t & (j - 1));
      int l = i | j;
      bool up = ((i & k) == 0);
      u64 ka = sk[i], kb = sk[l];
      u32 va = sv[i], vb = sv[l];
      if (comes_after(ka, va, kb, vb) == up) { sk[i] = kb; sv[i] = vb; sk[l] = ka; sv[l] = va; }
      prev_cross = cross;
    }
  }
  __syncthreads();
  for (int t = threadIdx.x; t < CHUNK; t += 512) { keys[base + t] = sk[t]; vals[base + t] = sv[t]; }
}

// r1: 64 lists x1024 -> 16 x4096 (A -> B), 4-way rank-merge (interleaved searches).
__global__ void k_merge1(const u64* __restrict__ Ak, const u32* __restrict__ Av,
                         u64* __restrict__ Bk, u32* __restrict__ Bv) {
  int gtid = blockIdx.x * blockDim.x + threadIdx.x;
  if (gtid >= NPAD) return;
  int lst = gtid >> 10, pos = gtid & 1023, grp = lst >> 2;
  u64 k = Ak[gtid]; u32 v = Av[gtid];
  int b0 = grp << 2;
  int q = lst & 3;
  int i0 = 0 + (0 >= q), i1 = 1 + (1 >= q), i2 = 2 + (2 >= q);
  const u64* K0 = Ak + (size_t)(b0 + i0) * 1024;
  const u64* K1 = Ak + (size_t)(b0 + i1) * 1024;
  const u64* K2 = Ak + (size_t)(b0 + i2) * 1024;
  const u32* V0 = Av + (size_t)(b0 + i0) * 1024;
  const u32* V1 = Av + (size_t)(b0 + i1) * 1024;
  const u32* V2 = Av + (size_t)(b0 + i2) * 1024;
  int lo0 = 0, hi0 = 1024, lo1 = 0, hi1 = 1024, lo2 = 0, hi2 = 1024;
  #pragma unroll
  for (int st = 0; st < 11; ++st) {
    int m0 = (lo0 + hi0) >> 1, m1 = (lo1 + hi1) >> 1, m2 = (lo2 + hi2) >> 1;
    int c0 = min(m0, 1023), c1 = min(m1, 1023), c2 = min(m2, 1023);
    u64 k0 = K0[c0], k1 = K1[c1], k2 = K2[c2];
    u32 v0 = V0[c0], v1 = V1[c1], v2 = V2[c2];
    if (lo0 < hi0) { if (before(k0, v0, k, v)) lo0 = m0 + 1; else hi0 = m0; }
    if (lo1 < hi1) { if (before(k1, v1, k, v)) lo1 = m1 + 1; else hi1 = m1; }
    if (lo2 < hi2) { if (before(k2, v2, k, v)) lo2 = m2 + 1; else hi2 = m2; }
  }
  int rank = pos + lo0 + lo1 + lo2;
  Bk[(size_t)grp * 4096 + rank] = k;
  Bv[(size_t)grp * 4096 + rank] = v;
}

// r2: 16 lists x4096 -> 4 x6144 (B -> A), truncated.
__global__ void k_merge2(const u64* __restrict__ Bk, const u32* __restrict__ Bv,
                         u64* __restrict__ Ak, u32* __restrict__ Av) {
  int gtid = blockIdx.x * blockDim.x + threadIdx.x;
  if (gtid >= NPAD) return;
  int lst = gtid >> 12, pos = gtid & 4095, grp = lst >> 2;
  u64 k = Bk[gtid]; u32 v = Bv[gtid];
  int b0 = grp << 2;
  int q = lst & 3;
  int i0 = 0 + (0 >= q), i1 = 1 + (1 >= q), i2 = 2 + (2 >= q);
  const u64* K0 = Bk + (size_t)(b0 + i0) * 4096;
  const u64* K1 = Bk + (size_t)(b0 + i1) * 4096;
  const u64* K2 = Bk + (size_t)(b0 + i2) * 4096;
  const u32* V0 = Bv + (size_t)(b0 + i0) * 4096;
  const u32* V1 = Bv + (size_t)(b0 + i1) * 4096;
  const u32* V2 = Bv + (size_t)(b0 + i2) * 4096;
  int lo0 = 0, hi0 = 4096, lo1 = 0, hi1 = 4096, lo2 = 0, hi2 = 4096;
  #pragma unroll
  for (int st = 0; st < 13; ++st) {
    int m0 = (lo0 + hi0) >> 1, m1 = (lo1 + hi1) >> 1, m2 = (lo2 + hi2) >> 1;
    int c0 = min(m0, 4095), c1 = min(m1, 4095), c2 = min(m2, 4095);
    u64 k0 = K0[c0], k1 = K1[c1], k2 = K2[c2];
    u32 v0 = V0[c0], v1 = V1[c1], v2 = V2[c2];
    if (lo0 < hi0) { if (before(k0, v0, k, v)) lo0 = m0 + 1; else hi0 = m0; }
    if (lo1 < hi1) { if (before(k1, v1, k, v)) lo1 = m1 + 1; else hi1 = m1; }
    if (lo2 < hi2) { if (before(k2, v2, k, v)) lo2 = m2 + 1; else hi2 = m2; }
  }
  int rank = pos + lo0 + lo1 + lo2;
  if (rank < CAP) { Ak[(size_t)grp * CAP + rank] = k; Av[(size_t)grp * CAP + rank] = v; }
}

// r3: 4 lists x6144 -> top-6000, fused with box decode into fboxes (float4).
// fboxes = (float) casts of the f64-decoded boxes == the reference's f32 boxes
// (verified: output absmax 0.0 with the identical cast).
__global__ void k_merge3(const u64* __restrict__ Ak, const u32* __restrict__ Av,
                         const float* __restrict__ bbox, const int* __restrict__ imh,
                         const int* __restrict__ imw, float4* __restrict__ fboxes) {
  int gtid = blockIdx.x * blockDim.x + threadIdx.x;
  if (gtid >= 4 * CAP) return;
  int lst = gtid / CAP, pos = gtid - lst * CAP;
  u64 k = Ak[gtid]; u32 v = Av[gtid];
  int i0 = 0 + (0 >= lst), i1 = 1 + (1 >= lst), i2 = 2 + (2 >= lst);
  const u64* K0 = Ak + (size_t)i0 * CAP;
  const u64* K1 = Ak + (size_t)i1 * CAP;
  const u64* K2 = Ak + (size_t)i2 * CAP;
  const u32* V0 = Av + (size_t)i0 * CAP;
  const u32* V1 = Av + (size_t)i1 * CAP;
  const u32* V2 = Av + (size_t)i2 * CAP;
  int lo0 = 0, hi0 = CAP, lo1 = 0, hi1 = CAP, lo2 = 0, hi2 = CAP;
  #pragma unroll
  for (int st = 0; st < 13; ++st) {
    int m0 = (lo0 + hi0) >> 1, m1 = (lo1 + hi1) >> 1, m2 = (lo2 + hi2) >> 1;
    int c0 = min(m0, CAP - 1), c1 = min(m1, CAP - 1), c2 = min(m2, CAP - 1);
    u64 k0 = K0[c0], k1 = K1[c1], k2 = K2[c2];
    u32 v0 = V0[c0], v1 = V1[c1], v2 = V2[c2];
    if (lo0 < hi0) { if (before(k0, v0, k, v)) lo0 = m0 + 1; else hi0 = m0; }
    if (lo1 < hi1) { if (before(k1, v1, k, v)) lo1 = m1 + 1; else hi1 = m1; }
    if (lo2 < hi2) { if (before(k2, v2, k, v)) lo2 = m2 + 1; else hi2 = m2; }
  }
  int rank = pos + lo0 + lo1 + lo2;
  if (rank < PRE_NMS) {
    double imh1 = (double)(imh[0] - 1);
    double imw1 = (double)(imw[0] - 1);
    BoxD b = decode_box((int)v, bbox, imw1, imh1);
    fboxes[rank] = make_float4((float)b.x1, (float)b.y1, (float)b.x2, (float)b.y2);
  }
}

// IoU mask in f32 mirroring the reference arithmetic exactly (same op order,
// IEEE f32 division, compare > 0.7f). Packed upper-tri rows + colC tiles.
__global__ void k_mask(const float4* __restrict__ fboxes, u64* __restrict__ mask,
                       u64* __restrict__ colC) {
  __shared__ float4 cb[64];
  int bc = blockIdx.x, br = blockIdx.y;
  int t = threadIdx.x;
  bool samechunk = (bc >> 2) == (br >> 2);
  if (bc < br) {
    if (samechunk) colC[(size_t)(((bc << 6) + t) * 4 + (br & 3))] = 0;
    return;
  }
  int j0 = bc * 64;
  int jt = j0 + t;
  cb[t] = (jt < PRE_NMS) ? fboxes[jt] : make_float4(0.f, 0.f, 0.f, 0.f);
  __syncthreads();
  int i = br * 64 + t;
  u64 bits = 0;
  if (i < PRE_NMS) {
    float4 rb = fboxes[i];
    float areai = (rb.z - rb.x) * (rb.w - rb.y);
    int cmax = min(64, PRE_NMS - j0);
    for (int c = 0; c < cmax; ++c) {
      int j = j0 + c;
      if (j <= i) continue;
      float4 cbx = cb[c];
      float xx1 = fmaxf(rb.x, cbx.x), yy1 = fmaxf(rb.y, cbx.y);
      float xx2 = fminf(rb.z, cbx.z), yy2 = fminf(rb.w, cbx.w);
      float w = fmaxf(xx2 - xx1, 0.0f), h = fmaxf(yy2 - yy1, 0.0f);
      float inter = w * h;
      float areaj = (cbx.z - cbx.x) * (cbx.w - cbx.y);
      float iou = inter / (areai + areaj - inter);
      if (iou > 0.7f) bits |= (1ULL << c);
    }
    mask[(size_t)(packed_off(i) + (bc - br))] = bits;
  }
  if (samechunk) {
    u64 colbits = 0;
    for (int j2 = 0; j2 < 64; ++j2) {
      u64 bl = __ballot(((bits >> j2) & 1ULL) != 0);
      if (t == j2) colbits = bl;
    }
    colC[(size_t)(((bc << 6) + t) * 4 + (br & 3))] = colbits;
  }
}

__device__ __forceinline__ u64 valid_word(int w) {
  int base = w << 6;
  if (base >= PRE_NMS) return 0ULL;
  if (base + 64 <= PRE_NMS) return ~0ULL;
  return (1ULL << (PRE_NMS - base)) - 1ULL;
}

// Greedy NMS scan, single wave. v7: gather-split — the OR-gather for chunk
// c+1 over keeps known BEFORE chunk c is issued ahead of chunk c's greedy
// (loads overlap RUN_WORDs); only the keeps ADDED during chunk c are gathered
// late (<=5 loads/lane, typically 1), then one combined shfl reduce. Gather
// addresses live in 5 persistent per-lane registers (lane l owns slots
// q*64+l), refreshed from keepA LDS as keeps are added.
__global__ __launch_bounds__(64) void k_scan(const u64* __restrict__ mask,
                                             const u64* __restrict__ colC,
                                             const float4* __restrict__ fboxes,
                                             float* __restrict__ out) {
  __shared__ int keepIdx[384];
  __shared__ int keepA[384];
  int lane = threadIdx.x;
  for (int r = lane; r < 384; r += 64) { keepIdx[r] = 0; keepA[r] = 0; }
  int nkeep = 0;
  bool done = false;
  int a0 = 0, a1 = 0, a2 = 0, a3 = 0, a4 = 0;  // per-lane gather addrs
  u64 or0 = 0, or1 = 0, or2 = 0, or3 = 0;      // OR over keeps, current chunk

  u64 ct00, ct01, ct02, ct03, ct10, ct11, ct12, ct13;
  u64 ct20, ct21, ct22, ct23, ct30, ct31, ct32, ct33;

#define COL_LOAD(cc, T, x0, x1, x2, x3)                                        \
  {                                                                            \
    int J_ = ((cc) << 8) + ((T) << 6) + lane;                                  \
    x0 = 0; x1 = 0; x2 = 0; x3 = 0;                                            \
    if (J_ < PRE_NMS) {                                                        \
      const ulonglong2* p_ = (const ulonglong2*)(colC + (size_t)J_ * 4);       \
      ulonglong2 u_ = p_[0], w_ = p_[1];                                       \
      x0 = u_.x; x1 = u_.y; x2 = w_.x; x3 = w_.y;                              \
    }                                                                          \
  }

  COL_LOAD(0, 0, ct00, ct01, ct02, ct03)
  COL_LOAD(0, 1, ct10, ct11, ct12, ct13)
  COL_LOAD(0, 2, ct20, ct21, ct22, ct23)
  COL_LOAD(0, 3, ct30, ct31, ct32, ct33)

  for (int c = 0; c < NCHUNK && !done; ++c) {
    int wbase = c << 2;
    int wnext = wbase + 4;
    bool gnext = (c + 1 < NCHUNK);
    bool tail_n = (wnext + 2) < NBLK;   // words wnext+2,3 exist (false for c=22)
    int oldn = nkeep;

    // prefetch next chunk's column tiles
    u64 n00 = 0, n01 = 0, n02 = 0, n03 = 0, n10 = 0, n11 = 0, n12 = 0, n13 = 0;
    u64 n20 = 0, n21 = 0, n22 = 0, n23 = 0, n30 = 0, n31 = 0, n32 = 0, n33 = 0;
    if (gnext) {
      COL_LOAD(c + 1, 0, n00, n01, n02, n03)
      COL_LOAD(c + 1, 1, n10, n11, n12, n13)
      COL_LOAD(c + 1, 2, n20, n21, n22, n23)
      COL_LOAD(c + 1, 3, n30, n31, n32, n33)
    }

    // EARLY gather for chunk c+1 over keeps known before this chunk
    u64 e0 = 0, e1 = 0, e2 = 0, e3 = 0;
    if (gnext) {
#define EGATHER(AA, LIM)                                                       \
      if ((LIM) < oldn) {                                                      \
        const u64* p_ = mask + (size_t)(AA) + wnext;                           \
        e0 |= p_[0]; e1 |= p_[1];                                              \
        if (tail_n) { e2 |= p_[2]; e3 |= p_[3]; }                              \
      }
      EGATHER(a0, lane)
      EGATHER(a1, 64 + lane)
      EGATHER(a2, 128 + lane)
      EGATHER(a3, 192 + lane)
      EGATHER(a4, 256 + lane)
#undef EGATHER
    }

    u64 kf0 = 0, kf1 = 0, kf2 = 0, kf3 = 0;

#define RUN_WORD(OR_, TT, DIAGC, CROSS_EXPR, KFVAR)                            \
    if (!done) {                                                               \
      u64 alive = ~(OR_) & valid_word(wbase + (TT));                           \
      alive &= ~__ballot((CROSS_EXPR) != 0ULL);                                \
      u64 kfacc = 0;                                                           \
      while (alive) {                                                          \
        int b = __builtin_ctzll(alive);                                        \
        u64 bb = 1ULL << b;                                                    \
        kfacc |= bb;                                                           \
        u64 sup_ = __ballot((((DIAGC) >> b) & 1ULL) != 0ULL);                  \
        alive &= ~(sup_ | bb);                                                 \
      }                                                                        \
      KFVAR = kfacc;                                                           \
      if (kfacc) {                                                             \
        if ((kfacc >> lane) & 1ULL) {                                          \
          int idx = nkeep + __popcll(kfacc & ((1ULL << lane) - 1ULL));         \
          if (idx < 384) {                                                     \
            int K = (c << 8) + ((TT) << 6) + lane;                             \
            keepIdx[idx] = K;                                                  \
            keepA[idx] = packed_off(K) - (K >> 6);                             \
          }                                                                    \
        }                                                                      \
        nkeep += __popcll(kfacc);                                              \
        if (nkeep >= POST_NMS) done = true;                                    \
      }                                                                        \
    }

    RUN_WORD(or0, 0, ct00, 0ULL, kf0)
    RUN_WORD(or1, 1, ct11, (ct10 & kf0), kf1)
    RUN_WORD(or2, 2, ct22, (ct20 & kf0) | (ct21 & kf1), kf2)
    RUN_WORD(or3, 3, ct33, (ct30 & kf0) | (ct31 & kf1) | (ct32 & kf2), kf3)
#undef RUN_WORD
    (void)kf3;

    // LATE gather: keeps added this chunk; refresh per-lane addr registers.
    if (gnext && !done) {
      int nk = min(nkeep, 384);
#define LGATHER(AR, SLOT)                                                      \
      {                                                                        \
        int s_ = (SLOT);                                                       \
        if (s_ >= oldn && s_ < nk) {                                           \
          AR = keepA[s_];                                                      \
          const u64* p_ = mask + (size_t)AR + wnext;                           \
          e0 |= p_[0]; e1 |= p_[1];                                            \
          if (tail_n) { e2 |= p_[2]; e3 |= p_[3]; }                            \
        }                                                                      \
      }
      LGATHER(a0, lane)
      LGATHER(a1, 64 + lane)
      LGATHER(a2, 128 + lane)
      LGATHER(a3, 192 + lane)
      LGATHER(a4, 256 + lane)
#undef LGATHER
      #pragma unroll
      for (int m = 32; m; m >>= 1) {
        e0 |= __shfl_xor(e0, m);
        e1 |= __shfl_xor(e1, m);
        e2 |= __shfl_xor(e2, m);
        e3 |= __shfl_xor(e3, m);
      }
      or0 = e0; or1 = e1; or2 = e2; or3 = e3;
    }

    ct00 = n00; ct01 = n01; ct02 = n02; ct03 = n03;
    ct10 = n10; ct11 = n11; ct12 = n12; ct13 = n13;
    ct20 = n20; ct21 = n21; ct22 = n22; ct23 = n23;
    ct30 = n30; ct31 = n31; ct32 = n32; ct33 = n33;
  }
#undef COL_LOAD
  __syncthreads();

  for (int r = lane; r < POST_NMS; r += 64) {
    int kk = keepIdx[r];
    float4 b = fboxes[kk];
    float* o = out + r * 5;
    o[0] = 0.0f;
    o[1] = b.x;
    o[2] = b.y;
    o[3] = b.z;
    o[4] = b.w;
  }
}

extern "C" void kernel_launch(void* const* d_in, const int* in_sizes, int n_in,
                              void* d_out, int out_size, void* d_ws, size_t ws_size,
                              hipStream_t stream) {
  const float* cls = (const float*)d_in[0];
  const float* bbox = (const float*)d_in[1];
  const int* imh = (const int*)d_in[2];
  const int* imw = (const int*)d_in[3];
  float* out = (float*)d_out;

  // Workspace (2.67 MB total, same extent as v6):
  // [0, 96256)           fboxes (6016 float4)
  // [96256, 288768)      colC   (6016 x 4 u64 column tiles)
  // [385024, 2670976)    packed upper-tri mask (285744 u64)
  //                      A/B key/val buffers (1.57MB) overlay the front of
  //                      the mask region (dead before k_mask runs).
  char* p = (char*)d_ws;
  float4* fboxes = (float4*)p;
  u64* colC = (u64*)(p + 96256);
  char* mb = p + 385024;
  u64* maskbuf = (u64*)mb;
  u64* Ak = (u64*)mb;                       // 65536 u64 (512 KB)
  u32* Av = (u32*)(mb + 524288);            // 65536 u32 (256 KB)
  u64* Bk = (u64*)(mb + 786432);            // 512 KB
  u32* Bv = (u32*)(mb + 1310720);           // 256 KB

  k_score_sort<<<64, 512, 0, stream>>>(cls, bbox, imh, imw, Ak, Av);
  k_merge1<<<NPAD / 256, 256, 0, stream>>>(Ak, Av, Bk, Bv);
  k_merge2<<<NPAD / 256, 256, 0, stream>>>(Bk, Bv, Ak, Av);
  k_merge3<<<(4 * CAP) / 256, 256, 0, stream>>>(Ak, Av, bbox, imh, imw, fboxes);
  k_mask<<<dim3(NBLK, NBLK), 64, 0, stream>>>(fboxes, maskbuf, colC);
  k_scan<<<1, 64, 0, stream>>>(maskbuf, colC, fboxes, out);
}